// Round 1
// baseline (521.917 us; speedup 1.0000x reference)
//
#include <hip/hip_runtime.h>
#include <hip/hip_fp16.h>

#define N_ROWS 8191
#define NO 8092
#define GSTRIDE 8192
#define SEG 512
#define WARM 96

#define OUT_UU  65480464ul
#define OUT_KF  65488655ul
#define OUT_KDF 65496846ul

#define WS_XB   134217728ul
#define WS_DIAG 136314880ul
#define WS_Q    136347648ul

typedef short bf16x8 __attribute__((ext_vector_type(8)));
typedef float f32x4  __attribute__((ext_vector_type(4)));

__device__ __forceinline__ float asin_core(float a) {
    // a in [-1+eps, 1-eps]; Cephes asinf, branch-free select
    float ax  = fabsf(a);
    bool  big = ax > 0.5f;
    float z   = big ? 0.5f * (1.0f - ax) : ax * ax;
    float x   = big ? sqrtf(z) : ax;
    float p = fmaf(z, 4.2163199048e-2f, 2.4181311049e-2f);
    p = fmaf(p, z, 4.5470025998e-2f);
    p = fmaf(p, z, 7.4953002686e-2f);
    p = fmaf(p, z, 1.6666752422e-1f);
    p = fmaf(p * z, x, x);
    float r = big ? fmaf(-2.0f, p, 1.57079632679489662f) : p;
    return copysignf(r, a);
}

__device__ __forceinline__ float kstep(float g, float kp, float m) {
    float uv  = fmaf(0.5f, g, fmaf(0.9f, kp, 0.1f));
    float arg = uv * m;
    arg = fminf(fmaxf(arg, -0.999999f), 0.999999f);
    return 0.63661977236758134f * asin_core(arg);
}

__device__ __forceinline__ unsigned short f2bf(float f) {
    unsigned int u = __float_as_uint(f);
    u = (u + 0x7FFFu + ((u >> 16) & 1u)) >> 16;
    return (unsigned short)u;
}

// ---- kernel 1: convert X (fp32) -> Xb (bf16), pad row 8191 with zeros ----
__global__ void k_convert(const float* __restrict__ X, unsigned short* __restrict__ Xb) {
    int idx = blockIdx.x * 256 + threadIdx.x;          // 0 .. 8192*128-1
    float v = (idx < N_ROWS * 128) ? X[idx] : 0.0f;
    Xb[idx] = f2bf(v);
}

// ---- kernel 2: diag[i] = ||x_i||^2 (one wave per row) ----
__global__ void k_diag(const float* __restrict__ X, float* __restrict__ diag) {
    int gwave = (blockIdx.x * 256 + threadIdx.x) >> 6;
    int lane  = threadIdx.x & 63;
    if (gwave >= N_ROWS) return;
    const float2* row = (const float2*)(X + (size_t)gwave * 128);
    float2 v = row[lane];
    float s = v.x * v.x + v.y * v.y;
    #pragma unroll
    for (int off = 32; off > 0; off >>= 1) s += __shfl_xor(s, off, 64);
    if (lane == 0) diag[gwave] = s;
}

// ---- kernel 3: diag scan (segmented, contraction lookahead) -> uu, q, k_diag_final ----
__global__ void k_scan_diag(const float* __restrict__ diag, float* __restrict__ q,
                            float* __restrict__ d_out) {
    int tid = threadIdx.x;                 // 256 threads, 32 outputs each
    int t0  = tid * 32;
    int tw  = max(0, t0 - 32);
    int te  = min(t0 + 32, N_ROWS);
    float kp = 0.0f;
    for (int t = tw; t < te; ++t) {
        float dg = diag[t];
        float uv = fmaf(0.5f, dg, fmaf(0.9f, kp, 0.1f));
        float s  = fabsf(fmaf(2.0f, uv, 1.0f));
        float arg = (uv + uv) / s;
        arg = fminf(fmaxf(arg, -0.999999f), 0.999999f);
        float k = 0.63661977236758134f * asin_core(arg);
        if (t >= t0) {
            d_out[OUT_UU + t] = uv;
            q[t] = 1.0f / sqrtf(s);
            if (t == N_ROWS - 1) d_out[OUT_KDF] = k;
        }
        kp = k;
    }
}

// ---- kernel 4: gram = Xb Xb^T (upper-tri 128x128 tiles, bf16 MFMA, fp16 out) ----
#define GP 136
__global__ __launch_bounds__(256) void k_gemm(const unsigned short* __restrict__ Xb,
                                              __half* __restrict__ gram) {
    int bi = blockIdx.y, bj = blockIdx.x;
    if (bj < bi) return;
    __shared__ short As[128 * GP];
    __shared__ short Bs[128 * GP];
    int tid = threadIdx.x;
    const uint4* ga = (const uint4*)(Xb + (size_t)bi * 128 * 128);
    const uint4* gb = (const uint4*)(Xb + (size_t)bj * 128 * 128);
    #pragma unroll
    for (int p = 0; p < 8; ++p) {
        int chunk = tid + p * 256;           // 2048 chunks of 16B per tile
        int row = chunk >> 4, c8 = chunk & 15;
        uint4 va = ga[row * 16 + c8];
        *(uint4*)&As[row * GP + c8 * 8] = va;
        uint4 vb = gb[row * 16 + c8];
        *(uint4*)&Bs[row * GP + c8 * 8] = vb;
    }
    __syncthreads();

    int lane = tid & 63, wave = tid >> 6;
    int wm = wave & 1, wn = wave >> 1;
    int lr = lane & 15, lk = lane >> 4;
    f32x4 acc[4][4];
    #pragma unroll
    for (int mi = 0; mi < 4; ++mi)
        #pragma unroll
        for (int ni = 0; ni < 4; ++ni) acc[mi][ni] = (f32x4){0.f, 0.f, 0.f, 0.f};

    #pragma unroll
    for (int kc = 0; kc < 4; ++kc) {
        bf16x8 a[4], b[4];
        #pragma unroll
        for (int mi = 0; mi < 4; ++mi)
            a[mi] = *(bf16x8*)&As[(wm * 64 + mi * 16 + lr) * GP + kc * 32 + lk * 8];
        #pragma unroll
        for (int ni = 0; ni < 4; ++ni)
            b[ni] = *(bf16x8*)&Bs[(wn * 64 + ni * 16 + lr) * GP + kc * 32 + lk * 8];
        #pragma unroll
        for (int mi = 0; mi < 4; ++mi)
            #pragma unroll
            for (int ni = 0; ni < 4; ++ni)
                acc[mi][ni] = __builtin_amdgcn_mfma_f32_16x16x32_bf16(a[mi], b[ni], acc[mi][ni], 0, 0, 0);
    }

    // C/D layout (m89-verified): col = lane&15, row = (lane>>4)*4 + reg
    int row0 = (lane >> 4) * 4, col = lane & 15;
    #pragma unroll
    for (int mi = 0; mi < 4; ++mi) {
        #pragma unroll
        for (int ni = 0; ni < 4; ++ni) {
            size_t gi = (size_t)bi * 128 + wm * 64 + mi * 16 + row0;
            size_t gj = (size_t)bj * 128 + wn * 64 + ni * 16 + col;
            f32x4 v = acc[mi][ni];
            #pragma unroll
            for (int r = 0; r < 4; ++r)
                gram[(gi + r) * GSTRIDE + gj] = __float2half(v[r]);
        }
    }
}

// ---- kernel 5: main diagonal-chain scan (upper triangle), segmented ----
__global__ __launch_bounds__(256) void k_scan_main(const __half* __restrict__ gram,
                                                   const float* __restrict__ q,
                                                   float* __restrict__ d_out) {
    int c = blockIdx.x * 256 + threadIdx.x;        // diagonal offset j-i
    if (c > NO - 1) return;                        // c <= 8091
    int tlim = N_ROWS - c;                         // exclusive bound on t
    int t0 = 99 + blockIdx.y * SEG;
    if (t0 >= tlim) return;
    int tend = min(t0 + SEG, tlim);
    int tw = t0 - WARM;                            // >= 3

    float kp = 0.0f;
    size_t gidx = (size_t)tw * GSTRIDE + tw + c;
    #pragma unroll 4
    for (int t = tw; t < t0; ++t, gidx += (GSTRIDE + 1)) {
        float g = __half2float(gram[gidx]);
        float m = 2.0f * q[t] * q[t + c];
        kp = kstep(g, kp, m);
    }
    size_t oidx = (size_t)(t0 - 99) * NO + (t0 + c - 99);
    #pragma unroll 4
    for (int t = t0; t < tend; ++t, gidx += (GSTRIDE + 1), oidx += (NO + 1)) {
        float g = __half2float(gram[gidx]);
        float m = 2.0f * q[t] * q[t + c];
        kp = kstep(g, kp, m);
        d_out[oidx] = fmaf(0.1f, g, kp);
    }
    if (tend == tlim) d_out[OUT_KF + (tlim - 1)] = kp;   // k_final[i] via symmetry
}

// ---- kernel 6: short diagonals (c >= 8092) only feed k_final[0..98], exact from t=0 ----
__global__ void k_short_diag(const __half* __restrict__ gram, const float* __restrict__ q,
                             float* __restrict__ d_out) {
    int l = threadIdx.x;
    if (l > 98) return;
    int c = NO + l;                 // 8092..8190
    int tl = N_ROWS - c;            // 1..99
    float kp = 0.0f;
    size_t gidx = (size_t)c;
    for (int t = 0; t < tl; ++t, gidx += (GSTRIDE + 1)) {
        float g = __half2float(gram[gidx]);
        float m = 2.0f * q[t] * q[t + c];
        kp = kstep(g, kp, m);
    }
    d_out[OUT_KF + (tl - 1)] = kp;
}

// ---- kernel 7: mirror upper -> strict lower (LDS transpose) ----
__global__ __launch_bounds__(256) void k_mirror(float* __restrict__ out) {
    int tc = blockIdx.x, tr = blockIdx.y;
    if (tr < tc) return;
    __shared__ float tile[32][33];
    int tx = threadIdx.x, ty = threadIdx.y;        // (32, 8)
    int sr0 = tc * 32, sc0 = tr * 32;
    #pragma unroll
    for (int k2 = 0; k2 < 32; k2 += 8) {
        int r = sr0 + ty + k2, cc = sc0 + tx;
        if (r < NO && cc < NO)
            tile[ty + k2][tx] = out[(size_t)r * NO + cc];
    }
    __syncthreads();
    int dr0 = tr * 32, dc0 = tc * 32;
    #pragma unroll
    for (int k2 = 0; k2 < 32; k2 += 8) {
        int r = dr0 + ty + k2, cc = dc0 + tx;
        if (r < NO && cc < NO && r > cc)
            out[(size_t)r * NO + cc] = tile[tx][ty + k2];
    }
}

extern "C" void kernel_launch(void* const* d_in, const int* in_sizes, int n_in,
                              void* d_out, int out_size, void* d_ws, size_t ws_size,
                              hipStream_t stream) {
    const float* X = (const float*)d_in[0];
    float* out = (float*)d_out;
    char* ws = (char*)d_ws;
    __half* gram = (__half*)ws;
    unsigned short* Xb = (unsigned short*)(ws + WS_XB);
    float* diag = (float*)(ws + WS_DIAG);
    float* q = (float*)(ws + WS_Q);

    k_convert<<<dim3(4096), dim3(256), 0, stream>>>(X, Xb);
    k_diag<<<dim3(2048), dim3(256), 0, stream>>>(X, diag);
    k_scan_diag<<<dim3(1), dim3(256), 0, stream>>>(diag, q, out);
    k_gemm<<<dim3(64, 64), dim3(256), 0, stream>>>(Xb, gram);
    k_scan_main<<<dim3(32, 16), dim3(256), 0, stream>>>(gram, q, out);
    k_short_diag<<<dim3(1), dim3(128), 0, stream>>>(gram, q, out);
    k_mirror<<<dim3(253, 253), dim3(32, 8), 0, stream>>>(out);
}